// Round 9
// baseline (1872.164 us; speedup 1.0000x reference)
//
#include <hip/hip_runtime.h>
#include <stdint.h>

typedef unsigned short ushort_t;
typedef short v8s __attribute__((ext_vector_type(8)));
typedef short v4s __attribute__((ext_vector_type(4)));
typedef float v4f __attribute__((ext_vector_type(4)));
typedef unsigned int uint32;

#define DIM   4096
#define NH    32
#define NKV   8
#define HD    128
#define SEQ   2048
#define BATCH 2
#define NTOK  (BATCH * SEQ)            // 4096 tokens
#define QKVN  (NH * HD + 2 * NKV * HD) // 6144 = 4096 Q + 1024 K + 1024 V
#define KOFF  (NH * HD)                // 4096
#define VOFF  (NH * HD + NKV * HD)     // 5120

__device__ __forceinline__ ushort_t f2bf(float f) {
    uint32 u = __float_as_uint(f);
    u += 0x7fff + ((u >> 16) & 1);   // RNE
    return (ushort_t)(u >> 16);
}
__device__ __forceinline__ float bf2f(ushort_t h) {
    return __uint_as_float(((uint32)h) << 16);
}
__device__ __forceinline__ void gl2lds16(const void* g, void* l) {
    __builtin_amdgcn_global_load_lds(
        (const __attribute__((address_space(1))) uint32*)g,
        (__attribute__((address_space(3))) uint32*)l, 16, 0, 0);
}
#if __has_builtin(__builtin_amdgcn_exp2f)
__device__ __forceinline__ float fast_exp2(float x) { return __builtin_amdgcn_exp2f(x); }
#else
__device__ __forceinline__ float fast_exp2(float x) { return exp2f(x); }
#endif

// 16x16x16 bf16 MFMA. __has_builtin for amdgcn builtins is 0 in the HOST pass,
// but the host pass still semantic-checks __global__ bodies -> stub must be
// __host__ __device__. Device pass picks the real builtin.
#if !defined(__HIP_DEVICE_COMPILE__)
__host__ __device__ static inline v4f MFMA_B16_K16(v4s a, v4s b, v4f c) {
    (void)a; (void)b; return c;  // host-pass stub, never executed
}
#elif __has_builtin(__builtin_amdgcn_mfma_f32_16x16x16_bf16)
#define MFMA_B16_K16(A, B, C) __builtin_amdgcn_mfma_f32_16x16x16_bf16(A, B, C, 0, 0, 0)
#elif __has_builtin(__builtin_amdgcn_mfma_f32_16x16x16bf16_1k)
#define MFMA_B16_K16(A, B, C) __builtin_amdgcn_mfma_f32_16x16x16bf16_1k(A, B, C, 0, 0, 0)
#else
#error "no 16x16x16 bf16 MFMA builtin on device"
#endif

// ---------------- fp32 -> bf16 convert (vectorized) ----------------
__global__ void cvt_f32_bf16(const float* __restrict__ src,
                             ushort_t* __restrict__ dst, int n4) {
    int i = blockIdx.x * blockDim.x + threadIdx.x;
    if (i >= n4) return;
    float4 v = ((const float4*)src)[i];
    uint32 lo = ((uint32)f2bf(v.y) << 16) | f2bf(v.x);
    uint32 hi = ((uint32)f2bf(v.w) << 16) | f2bf(v.z);
    ((uint2*)dst)[i] = make_uint2(lo, hi);
}

// ---------------- GEMM: C[M,N] = A[M,K] * B[N,K]^T, 256x256 4-phase/tile ----
// 8 waves (2Mx4N), BK=64, 128 KiB LDS double-buffer. v3 schedule (measured
// 211 us / MfmaUtil 42% on QKV):
//  - compiler-counted lgkm waits (no manual lgkmcnt(0) drains)
//  - 4 barriers/tile: end-ph1/ph2/ph3 + pre-MM4 (vmcnt proof)
//  - B-only register prefetch (B sets alternate roles per tile).
//    NOTE (round 7): adding an A ping-pong (v4) pushed operand VGPRs
//    96 -> spill past the 128-VGPR cap (acc holds 128 AGPRs of the
//    256-unified budget) -> scratch traffic (+57MB FETCH/+24MB WRITE),
//    gemm 211->524 us. Do NOT add operand sets to this kernel.
//  - vmcnt(6) once per tile proves ALL of tile T+1 before any wave reads it
template <int OUT_BF16>
__global__ __launch_bounds__(512, 2) void gemm_bt8(const ushort_t* __restrict__ A,
                                                   const ushort_t* __restrict__ B,
                                                   float* __restrict__ Cf,
                                                   ushort_t* __restrict__ Cb,
                                                   int M, int N, int K) {
    __shared__ ushort_t sm[2][2][16384];   // [buf][A|B][256 rows * 64] = 128 KiB
    const int t = threadIdx.x;
    const int w = t >> 6, lane = t & 63;
    const int g8 = lane >> 4, l16 = lane & 15;
    const int wr = w >> 2, wc = w & 3;     // 2 x 4 wave grid

    // XCD-aware swizzle (nwg % 8 == 0 for every launch in this file)
    const int gx = gridDim.x;
    const int nwg = gx * gridDim.y;
    const int wg0 = blockIdx.y * gx + blockIdx.x;
    const int swz = (wg0 & 7) * (nwg >> 3) + (wg0 >> 3);
    const int bm = swz % gx, bn = swz / gx;

    const ushort_t* Ab = A + (size_t)bm * 256 * K;
    const ushort_t* Bb = B + (size_t)bn * 256 * K;

    const int prt = t >> 3;
    const int gg  = (t & 7) ^ (prt & 7);
    const int rA0 = prt,                              rA1 = prt + 128;
    const int rB0 = ((prt >> 5) << 6) + (prt & 31),   rB1 = rB0 + 128;

    const int pgk  = g8 ^ (l16 & 7);          // pg at ks=0; ks=1 -> pgk^4
    const int aoff = (wr * 64 + l16) * 64;
    const int boff = (wc * 32 + l16) * 64;

#define STAGE_A(buf, ah, k0)                                                   \
  do {                                                                         \
    gl2lds16(&Ab[(size_t)(rA0 + (ah) * 64) * K + (k0) + gg * 8],               \
             &sm[buf][0][(ah) * 8192 + t * 8]);                                \
    gl2lds16(&Ab[(size_t)(rA1 + (ah) * 64) * K + (k0) + gg * 8],               \
             &sm[buf][0][(ah) * 8192 + 4096 + t * 8]);                         \
  } while (0)
#define STAGE_B(buf, bh, k0)                                                   \
  do {                                                                         \
    gl2lds16(&Bb[(size_t)(rB0 + (bh) * 32) * K + (k0) + gg * 8],               \
             &sm[buf][1][(bh) * 8192 + t * 8]);                                \
    gl2lds16(&Bb[(size_t)(rB1 + (bh) * 32) * K + (k0) + gg * 8],               \
             &sm[buf][1][(bh) * 8192 + 4096 + t * 8]);                         \
  } while (0)
#define LD_A(dst, buf, ihi)                                                    \
  do {                                                                         \
    _Pragma("unroll") for (int i_ = 0; i_ < 4; ++i_) {                         \
      (dst)[i_ * 2 + 0] = *(const v8s*)&sm[buf][0][(ihi) * 8192 + aoff + i_ * 1024 + pgk * 8];       \
      (dst)[i_ * 2 + 1] = *(const v8s*)&sm[buf][0][(ihi) * 8192 + aoff + i_ * 1024 + (pgk ^ 4) * 8]; \
    }                                                                          \
  } while (0)
#define LD_B(dst, buf, jhi)                                                    \
  do {                                                                         \
    _Pragma("unroll") for (int j_ = 0; j_ < 2; ++j_) {                         \
      (dst)[j_ * 2 + 0] = *(const v8s*)&sm[buf][1][(jhi) * 8192 + boff + j_ * 1024 + pgk * 8];       \
      (dst)[j_ * 2 + 1] = *(const v8s*)&sm[buf][1][(jhi) * 8192 + boff + j_ * 1024 + (pgk ^ 4) * 8]; \
    }                                                                          \
  } while (0)
#define MM(IHI, JHI, AF, BF)                                                   \
  do {                                                                         \
    __builtin_amdgcn_s_setprio(1);                                             \
    _Pragma("unroll") for (int k_ = 0; k_ < 2; ++k_)                           \
      _Pragma("unroll") for (int i_ = 0; i_ < 4; ++i_)                         \
        _Pragma("unroll") for (int j_ = 0; j_ < 2; ++j_)                       \
          acc[(IHI) * 4 + i_][(JHI) * 2 + j_] =                                \
              __builtin_amdgcn_mfma_f32_16x16x32_bf16(                         \
                  (AF)[i_ * 2 + k_], (BF)[j_ * 2 + k_],                        \
                  acc[(IHI) * 4 + i_][(JHI) * 2 + j_], 0, 0, 0);               \
    __builtin_amdgcn_s_setprio(0);                                             \
  } while (0)

// One K-tile: BF = LDS buffer, BL/BH = B-lo/B-hi register sets for this tile
// (they swap roles every tile; the ph4 prefetch fills next tile's BL = this
// tile's dead BH regs).
#define TILE_BODY(T, BF, BL, BH)                                               \
  do {                                                                         \
    const int Tp1 = (T) + 1, Tp2 = (T) + 2;                                    \
    /* ph1: read Alo + Bhi(this tile, ahead of ph2); stage B1(T+1) */          \
    LD_A(af, BF, 0);                                                           \
    LD_B(BH, BF, 1);                                                           \
    if (Tp1 < nk) STAGE_B((BF) ^ 1, 1, Tp1 << 6);                              \
    MM(0, 0, af, BL);                                                          \
    __builtin_amdgcn_s_barrier();                                              \
    /* ph2: no reads; stage A0(T+2) */                                         \
    if (Tp2 < nk) STAGE_A(BF, 0, Tp2 << 6);                                    \
    MM(0, 1, af, BH);                                                          \
    __builtin_amdgcn_s_barrier();                                              \
    /* ph3: read Ahi; stage B0(T+2) */                                         \
    LD_A(af, BF, 1);                                                           \
    if (Tp2 < nk) STAGE_B(BF, 0, Tp2 << 6);                                    \
    MM(1, 1, af, BH);                                                          \
    __builtin_amdgcn_s_barrier();                                              \
    /* ph4: stage A1(T+2); vmcnt proof for tile T+1; prefetch Blo(T+1) */      \
    if (Tp2 < nk) STAGE_A(BF, 1, Tp2 << 6);                                    \
    if ((T) < nk - 2) { asm volatile("s_waitcnt vmcnt(6)" ::: "memory"); }     \
    else              { asm volatile("s_waitcnt vmcnt(0)" ::: "memory"); }     \
    __builtin_amdgcn_s_barrier();                                              \
    if (Tp1 < nk) LD_B(BH, (BF) ^ 1, 0); /* next tile's Blo into dead BH */    \
    MM(1, 0, af, BL);                                                          \
    /* no barrier: MM(1,0) overlaps next tile's ph1 read/stage issue */        \
  } while (0)

    v4f acc[8][4];
    v4f z = {0.f, 0.f, 0.f, 0.f};
#pragma unroll
    for (int i = 0; i < 8; i++)
#pragma unroll
        for (int j = 0; j < 4; j++) acc[i][j] = z;
    v8s af[8], b0[4], b1[4];

    const int nk = K >> 6;

    // prologue: t0 {A0,B0,A1,B1} + t1 {A0,B0,A1}; B1(t1) issues at ph1(t0).
    STAGE_A(0, 0, 0);  STAGE_B(0, 0, 0);  STAGE_A(0, 1, 0);  STAGE_B(0, 1, 0);
    STAGE_A(1, 0, 64); STAGE_B(1, 0, 64); STAGE_A(1, 1, 64);
    asm volatile("s_waitcnt vmcnt(6)" ::: "memory");   // tile0 fully landed
    __builtin_amdgcn_s_barrier();
    LD_B(b0, 0, 0);    // Blo(t0)

    for (int T = 0; T < nk; T += 2) {
        TILE_BODY(T, 0, b0, b1);
        TILE_BODY(T + 1, 1, b1, b0);
    }

#undef STAGE_A
#undef STAGE_B
#undef LD_A
#undef LD_B
#undef MM
#undef TILE_BODY

    const int rowb = bm * 256 + wr * 128;
    const int colb = bn * 256 + wc * 64;
#pragma unroll
    for (int i = 0; i < 8; i++)
#pragma unroll
        for (int j = 0; j < 4; j++)
#pragma unroll
            for (int r = 0; r < 4; r++) {
                int row = rowb + i * 16 + g8 * 4 + r;
                int col = colb + j * 16 + l16;
                float v = acc[i][j][r];
                if (OUT_BF16)
                    Cb[(size_t)row * N + col] = f2bf(v);
                else
                    Cf[(size_t)row * N + col] = v;
            }
}

// ---------------- RoPE + reorg: qkv[tok][6144] -> Q[b,h,s,d], K[b,g,s,d] ----
// Q pre-scaled by (1/sqrt(HD)) * log2(e): softmax runs in exp2 domain.
__global__ __launch_bounds__(256) void rope_reorg(const ushort_t* __restrict__ qkv,
                                                  const float* __restrict__ fc,
                                                  const float* __restrict__ fs,
                                                  ushort_t* __restrict__ Qo,
                                                  ushort_t* __restrict__ Ko) {
    const int tok = blockIdx.x;
    const int bb = tok >> 11, s = tok & 2047;
    const ushort_t* base = qkv + (size_t)tok * QKVN;
    const int t = threadIdx.x;
    const float qscale = 0.08838834764831845f * 1.4426950408889634f;
    uint32* Qw = (uint32*)Qo;
    uint32* Kw = (uint32*)Ko;
#pragma unroll
    for (int i = 0; i < 8; ++i) {
        int p = i * 256 + t;
        int hh = p >> 6, pi = p & 63;
        float c = fc[s * 64 + pi], sn = fs[s * 64 + pi];
        uint32 u = *(const uint32*)&base[hh * 128 + 2 * pi];
        float t0 = bf2f((ushort_t)(u & 0xffff));
        float t1 = bf2f((ushort_t)(u >> 16));
        float o0 = (t0 * c - t1 * sn) * qscale;
        float o1 = (t0 * sn + t1 * c) * qscale;
        size_t dst = (((size_t)bb * NH + hh) * SEQ + s) * HD + 2 * pi;
        Qw[dst >> 1] = ((uint32)f2bf(o1) << 16) | f2bf(o0);
    }
#pragma unroll
    for (int i = 0; i < 2; ++i) {
        int p = i * 256 + t;
        int hh = p >> 6, pi = p & 63;
        float c = fc[s * 64 + pi], sn = fs[s * 64 + pi];
        uint32 u = *(const uint32*)&base[KOFF + hh * 128 + 2 * pi];
        float t0 = bf2f((ushort_t)(u & 0xffff));
        float t1 = bf2f((ushort_t)(u >> 16));
        float o0 = t0 * c - t1 * sn;
        float o1 = t0 * sn + t1 * c;
        size_t dst = (((size_t)bb * NKV + hh) * SEQ + s) * HD + 2 * pi;
        Kw[dst >> 1] = ((uint32)f2bf(o1) << 16) | f2bf(o0);
    }
}

// ---------------- V transpose: qkv V slice -> Vt[b,g,d,s] -------------------
// Plain layout (round-8's half-swap reverted: it was an LDS-bank artifact;
// attn now reads V directly from global, which doesn't care about LDS banks).
__global__ __launch_bounds__(256) void v_transpose(const ushort_t* __restrict__ qkv,
                                                   ushort_t* __restrict__ Vt) {
    __shared__ ushort_t tile[64][136];
    const int st = blockIdx.x, kvh = blockIdx.y, bb = blockIdx.z;
    const int t = threadIdx.x;
    const int s0 = st * 64;
#pragma unroll
    for (int i = 0; i < 4; ++i) {
        int c = i * 256 + t;
        int r = c >> 4, col8 = (c & 15) * 8;
        int tok = (bb << 11) + s0 + r;
        *(v8s*)&tile[r][col8] =
            *(const v8s*)&qkv[(size_t)tok * QKVN + VOFF + kvh * 128 + col8];
    }
    __syncthreads();
#pragma unroll
    for (int i = 0; i < 4; ++i) {
        int c = i * 256 + t;
        int d = c >> 3, s8 = (c & 7) * 8;
        ushort_t tmp[8];
#pragma unroll
        for (int j = 0; j < 8; j++) tmp[j] = tile[s8 + j][d];
        *(v8s*)&Vt[(((size_t)bb * NKV + kvh) * HD + d) * SEQ + s0 + s8] =
            *(v8s*)tmp;
    }
}

// ---------------- Flash attention (causal, GQA) -----------------------------
// STAGING-FREE: K+V for the whole problem is 16 MB = L2-resident (32 MB
// aggregate), so LDS staging + barriers + vmcnt were pure overhead (guide
// Common-mistake #7, m168->m169). Each wave reads K fragments (v8s, 64B
// coalesced segments) and V fragments (v4s) directly from global -> L1/L2.
// Waves are fully independent: per-wave causal trip count, no barriers, no
// LDS -> free software pipelining and 8-waves-per-block L1 reuse of the
// shared K/V stream. Compute path (S^T trick, deferred-PV, defer-max THR=8,
// accumulation order) is byte-identical to the round-5/8 kernel -> bitwise
// same results.
__global__ __launch_bounds__(512, 4) void attn_kernel(const ushort_t* __restrict__ Q,
                                                      const ushort_t* __restrict__ Kc,
                                                      const ushort_t* __restrict__ Vt,
                                                      ushort_t* __restrict__ Out) {
    const int qtb = gridDim.x - 1 - blockIdx.x;  // heavy blocks first
    const int h = blockIdx.y, bb = blockIdx.z;
    const int kvh = h >> 2;
    const int t = threadIdx.x, w = t >> 6, lane = t & 63;
    const int g8 = lane >> 4, l16 = lane & 15;
    const int R = qtb * 128 + w * 16;      // wave q-tile base
    const int qrow = R + l16;              // this lane's softmax row

    const size_t qb = (((size_t)bb * NH + h) * SEQ + R) * HD;
    v8s qf[4];
#pragma unroll
    for (int ks = 0; ks < 4; ++ks)
        qf[ks] = *(const v8s*)&Q[qb + (size_t)l16 * HD + ks * 32 + g8 * 8];

    float m_i = -3.0e38f, l_i = 0.f;
    v4f z = {0.f, 0.f, 0.f, 0.f};
    v4f o[8];
#pragma unroll
    for (int n = 0; n < 8; n++) o[n] = z;

    v4s pjp[4];              // P(t-1) carried in registers
    float alo_p[4] = {1.f, 1.f, 1.f, 1.f};
    int skip_p = 1;

    const ushort_t* Kbase = Kc + ((size_t)bb * NKV + kvh) * SEQ * HD;
    // per-lane V base: row d = n*16+l16, key column varies
    const ushort_t* Vl = Vt + ((size_t)bb * NKV + kvh) * HD * SEQ
                            + (size_t)l16 * SEQ + g8 * 4;

    const int nkt = (R >> 6) + 1;          // per-wave causal trip count
    for (int kt = 0; kt < nkt; ++kt) {
        const int k0 = kt * 64;
        const ushort_t* Kt = Kbase + (size_t)(k0 + l16) * HD + g8 * 8;

        // ---- QK(t): S^T tiles; lane: q=l16, key=g8*4+r (direct from L1/L2)
        v4f s[4];
#pragma unroll
        for (int j = 0; j < 4; j++) s[j] = z;
        __builtin_amdgcn_s_setprio(1);
#pragma unroll
        for (int j = 0; j < 4; j++)
#pragma unroll
            for (int ks = 0; ks < 4; ks++) {
                const v8s kb_ = *(const v8s*)&Kt[(size_t)(j * 16) * HD + ks * 32];
                s[j] = __builtin_amdgcn_mfma_f32_16x16x32_bf16(kb_, qf[ks], s[j], 0, 0, 0);
            }
        __builtin_amdgcn_s_setprio(0);

        // ---- deferred rescale + PV(t-1): independent of softmax(t)
        if (kt) {
            const int kp = k0 - 64;
            if (!skip_p) {
#pragma unroll
                for (int n = 0; n < 8; n++)
#pragma unroll
                    for (int r = 0; r < 4; r++) o[n][r] *= alo_p[r];
            }
            __builtin_amdgcn_s_setprio(1);
#pragma unroll
            for (int j = 0; j < 4; j++)
#pragma unroll
                for (int n = 0; n < 8; n++) {
                    const v4s vb_ = *(const v4s*)&Vl[(size_t)(n * 16) * SEQ + kp + j * 16];
                    o[n] = MFMA_B16_K16(pjp[j], vb_, o[n]);
                }
            __builtin_amdgcn_s_setprio(0);
        }

        if (kt == nkt - 1) {  // diagonal tile: causal mask (wave-uniform)
#pragma unroll
            for (int j = 0; j < 4; j++)
#pragma unroll
                for (int r = 0; r < 4; r++) {
                    int key = k0 + j * 16 + g8 * 4 + r;
                    if (key > qrow) s[j][r] = -3.0e38f;
                }
        }

        // ---- softmax(t): per-lane max + 2-shfl butterfly across g8 copies
        float mx = fmaxf(fmaxf(s[0][0], s[0][1]), fmaxf(s[0][2], s[0][3]));
#pragma unroll
        for (int j = 1; j < 4; j++)
            mx = fmaxf(mx, fmaxf(fmaxf(s[j][0], s[j][1]), fmaxf(s[j][2], s[j][3])));
        mx = fmaxf(mx, __shfl_xor(mx, 16, 64));
        mx = fmaxf(mx, __shfl_xor(mx, 32, 64));

        const int skip = __all(mx - m_i <= 8.0f);   // defer-max (exp2 domain)
        float alpha = 1.f;
        if (!skip) {
            float mnew = fmaxf(m_i, mx);
            alpha = fast_exp2(m_i - mnew);
            m_i = mnew;
        }

        float sum = 0.f;
#pragma unroll
        for (int j = 0; j < 4; j++)
#pragma unroll
            for (int r = 0; r < 4; r++) {
                float p = fast_exp2(s[j][r] - m_i);
                sum += p;
                pjp[j][r] = (short)f2bf(p);
            }
        sum += __shfl_xor(sum, 16, 64);
        sum += __shfl_xor(sum, 32, 64);
        l_i = l_i * alpha + sum;

        if (!skip) {   // O-row alphas live in lanes 0-15 (rows g8*4+r)
#pragma unroll
            for (int r = 0; r < 4; r++) alo_p[r] = __shfl(alpha, g8 * 4 + r, 64);
        }
        skip_p = skip;
    }

    // ---- final deferred PV(nkt-1)
    {
        const int kp = (nkt - 1) * 64;
        if (!skip_p) {
#pragma unroll
            for (int n = 0; n < 8; n++)
#pragma unroll
                for (int r = 0; r < 4; r++) o[n][r] *= alo_p[r];
        }
#pragma unroll
        for (int j = 0; j < 4; j++)
#pragma unroll
            for (int n = 0; n < 8; n++) {
                const v4s vb_ = *(const v4s*)&Vl[(size_t)(n * 16) * SEQ + kp + j * 16];
                o[n] = MFMA_B16_K16(pjp[j], vb_, o[n]);
            }
    }

    // epilogue: Out[b][s][h][d]; O row g8*4+r = q, col l16 (+16n) = d
    float lo[4];
#pragma unroll
    for (int r = 0; r < 4; r++) lo[r] = __shfl(l_i, g8 * 4 + r, 64);
#pragma unroll
    for (int n = 0; n < 8; n++)
#pragma unroll
        for (int r = 0; r < 4; r++) {
            int row = R + g8 * 4 + r;
            int col = n * 16 + l16;
            Out[(((size_t)bb * SEQ + row) * NH + h) * HD + col] = f2bf(o[n][r] / lo[r]);
        }
}

// ---------------- launch ----------------------------------------------------
extern "C" void kernel_launch(void* const* d_in, const int* in_sizes, int n_in,
                              void* d_out, int out_size, void* d_ws, size_t ws_size,
                              hipStream_t stream) {
    const float* x  = (const float*)d_in[0];
    const float* wq = (const float*)d_in[1];
    const float* wk = (const float*)d_in[2];
    const float* wv = (const float*)d_in[3];
    const float* wo = (const float*)d_in[4];
    const float* fc = (const float*)d_in[5];
    const float* fs = (const float*)d_in[6];
    float* out = (float*)d_out;

    ushort_t* ws = (ushort_t*)d_ws;
    size_t off = 0;
    ushort_t* xb    = ws + off; off += (size_t)NTOK * DIM;   // reused as attn_out
    ushort_t* wqkvb = ws + off; off += (size_t)QKVN * DIM;
    ushort_t* wob   = ws + off; off += (size_t)DIM * DIM;
    ushort_t* qkv   = ws + off; off += (size_t)NTOK * QKVN;
    ushort_t* Qb    = ws + off; off += (size_t)BATCH * NH * SEQ * HD;
    ushort_t* Kb    = ws + off; off += (size_t)BATCH * NKV * SEQ * HD;
    ushort_t* Vt    = ws + off; off += (size_t)BATCH * NKV * HD * SEQ;
    ushort_t* attn_out = xb;  // x dead after QKV GEMM

    cvt_f32_bf16<<<(NTOK * DIM / 4) / 256, 256, 0, stream>>>(x, xb, NTOK * DIM / 4);
    cvt_f32_bf16<<<(DIM * DIM / 4) / 256, 256, 0, stream>>>(wq, wqkvb, DIM * DIM / 4);
    cvt_f32_bf16<<<(NKV * HD * DIM / 4) / 256, 256, 0, stream>>>(
        wk, wqkvb + (size_t)KOFF * DIM, NKV * HD * DIM / 4);
    cvt_f32_bf16<<<(NKV * HD * DIM / 4) / 256, 256, 0, stream>>>(
        wv, wqkvb + (size_t)VOFF * DIM, NKV * HD * DIM / 4);
    cvt_f32_bf16<<<(DIM * DIM / 4) / 256, 256, 0, stream>>>(wo, wob, DIM * DIM / 4);

    dim3 g1(NTOK / 256, QKVN / 256);   // (16, 24) = 384 wgs, %8 == 0
    gemm_bt8<1><<<g1, 512, 0, stream>>>(xb, wqkvb, nullptr, qkv, NTOK, QKVN, DIM);

    rope_reorg<<<NTOK, 256, 0, stream>>>(qkv, fc, fs, Qb, Kb);
    dim3 gv(SEQ / 64, NKV, BATCH);
    v_transpose<<<gv, 256, 0, stream>>>(qkv, Vt);

    dim3 ga(SEQ / 128, NH, BATCH);     // 128 q-rows per block, 8 waves
    attn_kernel<<<ga, 512, 0, stream>>>(Qb, Kb, Vt, attn_out);

    dim3 g2(NTOK / 256, DIM / 256);    // (16, 16) = 256 wgs, %8 == 0
    gemm_bt8<0><<<g2, 512, 0, stream>>>(attn_out, wob, out, nullptr, NTOK, DIM, DIM);
}

// Round 10
// 750.752 us; speedup vs baseline: 2.4937x; 2.4937x over previous
//
#include <hip/hip_runtime.h>
#include <stdint.h>

typedef unsigned short ushort_t;
typedef short v8s __attribute__((ext_vector_type(8)));
typedef short v4s __attribute__((ext_vector_type(4)));
typedef float v4f __attribute__((ext_vector_type(4)));
typedef unsigned int uint32;

#define DIM   4096
#define NH    32
#define NKV   8
#define HD    128
#define SEQ   2048
#define BATCH 2
#define NTOK  (BATCH * SEQ)            // 4096 tokens
#define QKVN  (NH * HD + 2 * NKV * HD) // 6144 = 4096 Q + 1024 K + 1024 V
#define KOFF  (NH * HD)                // 4096
#define VOFF  (NH * HD + NKV * HD)     // 5120

__device__ __forceinline__ ushort_t f2bf(float f) {
    uint32 u = __float_as_uint(f);
    u += 0x7fff + ((u >> 16) & 1);   // RNE
    return (ushort_t)(u >> 16);
}
__device__ __forceinline__ float bf2f(ushort_t h) {
    return __uint_as_float(((uint32)h) << 16);
}
__device__ __forceinline__ void gl2lds16(const void* g, void* l) {
    __builtin_amdgcn_global_load_lds(
        (const __attribute__((address_space(1))) uint32*)g,
        (__attribute__((address_space(3))) uint32*)l, 16, 0, 0);
}
#if __has_builtin(__builtin_amdgcn_exp2f)
__device__ __forceinline__ float fast_exp2(float x) { return __builtin_amdgcn_exp2f(x); }
#else
__device__ __forceinline__ float fast_exp2(float x) { return exp2f(x); }
#endif

// 16x16x16 bf16 MFMA. __has_builtin for amdgcn builtins is 0 in the HOST pass,
// but the host pass still semantic-checks __global__ bodies -> stub must be
// __host__ __device__. Device pass picks the real builtin.
#if !defined(__HIP_DEVICE_COMPILE__)
__host__ __device__ static inline v4f MFMA_B16_K16(v4s a, v4s b, v4f c) {
    (void)a; (void)b; return c;  // host-pass stub, never executed
}
#elif __has_builtin(__builtin_amdgcn_mfma_f32_16x16x16_bf16)
#define MFMA_B16_K16(A, B, C) __builtin_amdgcn_mfma_f32_16x16x16_bf16(A, B, C, 0, 0, 0)
#elif __has_builtin(__builtin_amdgcn_mfma_f32_16x16x16bf16_1k)
#define MFMA_B16_K16(A, B, C) __builtin_amdgcn_mfma_f32_16x16x16bf16_1k(A, B, C, 0, 0, 0)
#else
#error "no 16x16x16 bf16 MFMA builtin on device"
#endif

// ---------------- fp32 -> bf16 convert (vectorized) ----------------
__global__ void cvt_f32_bf16(const float* __restrict__ src,
                             ushort_t* __restrict__ dst, int n4) {
    int i = blockIdx.x * blockDim.x + threadIdx.x;
    if (i >= n4) return;
    float4 v = ((const float4*)src)[i];
    uint32 lo = ((uint32)f2bf(v.y) << 16) | f2bf(v.x);
    uint32 hi = ((uint32)f2bf(v.w) << 16) | f2bf(v.z);
    ((uint2*)dst)[i] = make_uint2(lo, hi);
}

// ---------------- GEMM: C[M,N] = A[M,K] * B[N,K]^T, 256x256 4-phase/tile ----
// 8 waves (2Mx4N), BK=64, 128 KiB LDS double-buffer. v5 schedule = v3 +
// ZERO-REGISTER A-read reorder (no extra operand sets -- round-7 NOTE):
//  - MM order 00,01,11,10; Alo lives ph1-ph2, Ahi lives ph3-ph4 in ONE af set.
//  - LD_A(Ahi) issued at END of ph2 (WAR after MM01 issues) -> lands during
//    ph2-barrier + ph3 stage issue, ready for MM11.
//  - LD_A(Alo,T+1) issued at END of ph4 (after vmcnt-proof barrier + MM10
//    issues) -> lands during MM10 drain, ready for next ph1's MM00.
//  - Every MM's operands now have >=1 MM-cluster of lead time; v3 stalled
//    ~250cy at ph1/ph3 on same-phase LD_A.
//  NOTE (round 7): do NOT add operand register sets: af 64+b 32 VGPRs spills
//  past the 128-VGPR cap (acc = 128 AGPRs of the 256-unified file) ->
//  scratch traffic, gemm 211->524 us.
//  Hazards (verified): BF[A1] read ph2-end, consumed ph3 (lgkm), overwritten
//  ph4 stage (post-ph3-barrier). BF^1[A0] read ph4-end, consumed next-ph1
//  (lgkm), overwritten next-ph2 stage (post-ph1-barrier). vmcnt(6) at ph4
//  drains everything except {A0,B0,A1}(T+2) -> tile T+1 fully landed.
template <int OUT_BF16>
__global__ __launch_bounds__(512, 2) void gemm_bt8(const ushort_t* __restrict__ A,
                                                   const ushort_t* __restrict__ B,
                                                   float* __restrict__ Cf,
                                                   ushort_t* __restrict__ Cb,
                                                   int M, int N, int K) {
    __shared__ ushort_t sm[2][2][16384];   // [buf][A|B][256 rows * 64] = 128 KiB
    const int t = threadIdx.x;
    const int w = t >> 6, lane = t & 63;
    const int g8 = lane >> 4, l16 = lane & 15;
    const int wr = w >> 2, wc = w & 3;     // 2 x 4 wave grid

    // XCD-aware swizzle (nwg % 8 == 0 for every launch in this file)
    const int gx = gridDim.x;
    const int nwg = gx * gridDim.y;
    const int wg0 = blockIdx.y * gx + blockIdx.x;
    const int swz = (wg0 & 7) * (nwg >> 3) + (wg0 >> 3);
    const int bm = swz % gx, bn = swz / gx;

    const ushort_t* Ab = A + (size_t)bm * 256 * K;
    const ushort_t* Bb = B + (size_t)bn * 256 * K;

    const int prt = t >> 3;
    const int gg  = (t & 7) ^ (prt & 7);
    const int rA0 = prt,                              rA1 = prt + 128;
    const int rB0 = ((prt >> 5) << 6) + (prt & 31),   rB1 = rB0 + 128;

    const int pgk  = g8 ^ (l16 & 7);          // pg at ks=0; ks=1 -> pgk^4
    const int aoff = (wr * 64 + l16) * 64;
    const int boff = (wc * 32 + l16) * 64;

#define STAGE_A(buf, ah, k0)                                                   \
  do {                                                                         \
    gl2lds16(&Ab[(size_t)(rA0 + (ah) * 64) * K + (k0) + gg * 8],               \
             &sm[buf][0][(ah) * 8192 + t * 8]);                                \
    gl2lds16(&Ab[(size_t)(rA1 + (ah) * 64) * K + (k0) + gg * 8],               \
             &sm[buf][0][(ah) * 8192 + 4096 + t * 8]);                         \
  } while (0)
#define STAGE_B(buf, bh, k0)                                                   \
  do {                                                                         \
    gl2lds16(&Bb[(size_t)(rB0 + (bh) * 32) * K + (k0) + gg * 8],               \
             &sm[buf][1][(bh) * 8192 + t * 8]);                                \
    gl2lds16(&Bb[(size_t)(rB1 + (bh) * 32) * K + (k0) + gg * 8],               \
             &sm[buf][1][(bh) * 8192 + 4096 + t * 8]);                         \
  } while (0)
#define LD_A(dst, buf, ihi)                                                    \
  do {                                                                         \
    _Pragma("unroll") for (int i_ = 0; i_ < 4; ++i_) {                         \
      (dst)[i_ * 2 + 0] = *(const v8s*)&sm[buf][0][(ihi) * 8192 + aoff + i_ * 1024 + pgk * 8];       \
      (dst)[i_ * 2 + 1] = *(const v8s*)&sm[buf][0][(ihi) * 8192 + aoff + i_ * 1024 + (pgk ^ 4) * 8]; \
    }                                                                          \
  } while (0)
#define LD_B(dst, buf, jhi)                                                    \
  do {                                                                         \
    _Pragma("unroll") for (int j_ = 0; j_ < 2; ++j_) {                         \
      (dst)[j_ * 2 + 0] = *(const v8s*)&sm[buf][1][(jhi) * 8192 + boff + j_ * 1024 + pgk * 8];       \
      (dst)[j_ * 2 + 1] = *(const v8s*)&sm[buf][1][(jhi) * 8192 + boff + j_ * 1024 + (pgk ^ 4) * 8]; \
    }                                                                          \
  } while (0)
#define MM(IHI, JHI, AF, BF)                                                   \
  do {                                                                         \
    __builtin_amdgcn_s_setprio(1);                                             \
    _Pragma("unroll") for (int k_ = 0; k_ < 2; ++k_)                           \
      _Pragma("unroll") for (int i_ = 0; i_ < 4; ++i_)                         \
        _Pragma("unroll") for (int j_ = 0; j_ < 2; ++j_)                       \
          acc[(IHI) * 4 + i_][(JHI) * 2 + j_] =                                \
              __builtin_amdgcn_mfma_f32_16x16x32_bf16(                         \
                  (AF)[i_ * 2 + k_], (BF)[j_ * 2 + k_],                        \
                  acc[(IHI) * 4 + i_][(JHI) * 2 + j_], 0, 0, 0);               \
    __builtin_amdgcn_s_setprio(0);                                             \
  } while (0)

// One K-tile. af holds Alo(T) on entry (loaded at prev ph4-end); BL/BH swap
// roles every tile (2-tile unroll).
#define TILE_BODY(T, BF, BL, BH)                                               \
  do {                                                                         \
    const int Tp1 = (T) + 1, Tp2 = (T) + 2;                                    \
    /* ph1: read Bhi; stage B1(T+1); MM00 uses preloaded af(Alo)+BL */         \
    LD_B(BH, BF, 1);                                                           \
    if (Tp1 < nk) STAGE_B((BF) ^ 1, 1, Tp1 << 6);                              \
    MM(0, 0, af, BL);                                                          \
    __builtin_amdgcn_s_barrier();                                              \
    /* ph2: stage A0(T+2); MM01 last use of Alo; then af <- Ahi (WAR) */       \
    if (Tp2 < nk) STAGE_A(BF, 0, Tp2 << 6);                                    \
    MM(0, 1, af, BH);                                                          \
    LD_A(af, BF, 1);                                                           \
    __builtin_amdgcn_s_barrier();                                              \
    /* ph3: stage B0(T+2); MM11 uses af(Ahi, loaded ph2-end) */                \
    if (Tp2 < nk) STAGE_B(BF, 0, Tp2 << 6);                                    \
    MM(1, 1, af, BH);                                                          \
    __builtin_amdgcn_s_barrier();                                              \
    /* ph4: stage A1(T+2); vmcnt proof; MM10 last use of Ahi+BL; then */       \
    /* prefetch next tile's Blo and Alo (buffer proven by the barrier) */      \
    if (Tp2 < nk) STAGE_A(BF, 1, Tp2 << 6);                                    \
    if ((T) < nk - 2) { asm volatile("s_waitcnt vmcnt(6)" ::: "memory"); }     \
    else              { asm volatile("s_waitcnt vmcnt(0)" ::: "memory"); }     \
    __builtin_amdgcn_s_barrier();                                              \
    if (Tp1 < nk) LD_B(BH, (BF) ^ 1, 0); /* next Blo into dead BH */           \
    MM(1, 0, af, BL);                                                          \
    if (Tp1 < nk) LD_A(af, (BF) ^ 1, 0); /* next Alo into af (WAR) */          \
    /* no barrier: MM(1,0) overlaps next tile's ph1 issue */                   \
  } while (0)

    v4f acc[8][4];
    v4f z = {0.f, 0.f, 0.f, 0.f};
#pragma unroll
    for (int i = 0; i < 8; i++)
#pragma unroll
        for (int j = 0; j < 4; j++) acc[i][j] = z;
    v8s af[8], b0[4], b1[4];

    const int nk = K >> 6;

    // prologue: t0 {A0,B0,A1,B1} + t1 {A0,B0,A1}; B1(t1) issues at ph1(t0).
    STAGE_A(0, 0, 0);  STAGE_B(0, 0, 0);  STAGE_A(0, 1, 0);  STAGE_B(0, 1, 0);
    STAGE_A(1, 0, 64); STAGE_B(1, 0, 64); STAGE_A(1, 1, 64);
    asm volatile("s_waitcnt vmcnt(6)" ::: "memory");   // tile0 fully landed
    __builtin_amdgcn_s_barrier();
    LD_A(af, 0, 0);    // Alo(t0)
    LD_B(b0, 0, 0);    // Blo(t0)

    for (int T = 0; T < nk; T += 2) {
        TILE_BODY(T, 0, b0, b1);
        TILE_BODY(T + 1, 1, b1, b0);
    }

#undef STAGE_A
#undef STAGE_B
#undef LD_A
#undef LD_B
#undef MM
#undef TILE_BODY

    const int rowb = bm * 256 + wr * 128;
    const int colb = bn * 256 + wc * 64;
#pragma unroll
    for (int i = 0; i < 8; i++)
#pragma unroll
        for (int j = 0; j < 4; j++)
#pragma unroll
            for (int r = 0; r < 4; r++) {
                int row = rowb + i * 16 + g8 * 4 + r;
                int col = colb + j * 16 + l16;
                float v = acc[i][j][r];
                if (OUT_BF16)
                    Cb[(size_t)row * N + col] = f2bf(v);
                else
                    Cf[(size_t)row * N + col] = v;
            }
}

// ---------------- RoPE + reorg: qkv[tok][6144] -> Q[b,h,s,d], K[b,g,s,d] ----
// Q pre-scaled by (1/sqrt(HD)) * log2(e): softmax runs in exp2 domain.
__global__ __launch_bounds__(256) void rope_reorg(const ushort_t* __restrict__ qkv,
                                                  const float* __restrict__ fc,
                                                  const float* __restrict__ fs,
                                                  ushort_t* __restrict__ Qo,
                                                  ushort_t* __restrict__ Ko) {
    const int tok = blockIdx.x;
    const int bb = tok >> 11, s = tok & 2047;
    const ushort_t* base = qkv + (size_t)tok * QKVN;
    const int t = threadIdx.x;
    const float qscale = 0.08838834764831845f * 1.4426950408889634f;
    uint32* Qw = (uint32*)Qo;
    uint32* Kw = (uint32*)Ko;
#pragma unroll
    for (int i = 0; i < 8; ++i) {
        int p = i * 256 + t;
        int hh = p >> 6, pi = p & 63;
        float c = fc[s * 64 + pi], sn = fs[s * 64 + pi];
        uint32 u = *(const uint32*)&base[hh * 128 + 2 * pi];
        float t0 = bf2f((ushort_t)(u & 0xffff));
        float t1 = bf2f((ushort_t)(u >> 16));
        float o0 = (t0 * c - t1 * sn) * qscale;
        float o1 = (t0 * sn + t1 * c) * qscale;
        size_t dst = (((size_t)bb * NH + hh) * SEQ + s) * HD + 2 * pi;
        Qw[dst >> 1] = ((uint32)f2bf(o1) << 16) | f2bf(o0);
    }
#pragma unroll
    for (int i = 0; i < 2; ++i) {
        int p = i * 256 + t;
        int hh = p >> 6, pi = p & 63;
        float c = fc[s * 64 + pi], sn = fs[s * 64 + pi];
        uint32 u = *(const uint32*)&base[KOFF + hh * 128 + 2 * pi];
        float t0 = bf2f((ushort_t)(u & 0xffff));
        float t1 = bf2f((ushort_t)(u >> 16));
        float o0 = t0 * c - t1 * sn;
        float o1 = t0 * sn + t1 * c;
        size_t dst = (((size_t)bb * NKV + hh) * SEQ + s) * HD + 2 * pi;
        Kw[dst >> 1] = ((uint32)f2bf(o1) << 16) | f2bf(o0);
    }
}

// ---------------- V transpose: qkv V slice -> Vt[b,g,d,s] -------------------
// Rows with (d&8) store each 16B granule with its two 8B halves SWAPPED:
// pairs with the attn V-read sub-granule offset for conflict-free ds_read
// (round 8: SQ_LDS_BANK_CONFLICT 1.78e7 -> 0). Verified value-correct on HW.
__global__ __launch_bounds__(256) void v_transpose(const ushort_t* __restrict__ qkv,
                                                   ushort_t* __restrict__ Vt) {
    __shared__ ushort_t tile[64][136];
    const int st = blockIdx.x, kvh = blockIdx.y, bb = blockIdx.z;
    const int t = threadIdx.x;
    const int s0 = st * 64;
#pragma unroll
    for (int i = 0; i < 4; ++i) {
        int c = i * 256 + t;
        int r = c >> 4, col8 = (c & 15) * 8;
        int tok = (bb << 11) + s0 + r;
        *(v8s*)&tile[r][col8] =
            *(const v8s*)&qkv[(size_t)tok * QKVN + VOFF + kvh * 128 + col8];
    }
    __syncthreads();
#pragma unroll
    for (int i = 0; i < 4; ++i) {
        int c = i * 256 + t;
        int d = c >> 3, s8 = (c & 7) * 8;
        const int hswap = (d & 8) ? 4 : 0;   // swap 8B halves for odd-8 rows
        ushort_t tmp[8];
#pragma unroll
        for (int j = 0; j < 8; j++) tmp[j] = tile[s8 + (j ^ hswap)][d];
        *(v8s*)&Vt[(((size_t)bb * NKV + kvh) * HD + d) * SEQ + s0 + s8] =
            *(v8s*)tmp;
    }
}

// ---------------- Flash attention (causal, GQA) -----------------------------
// ROUND-8 VERSION (best measured: part of the 753us total). Round 9's
// staging-free variant was 5.3x SLOWER (MfmaUtil 3%): per-lane fragment
// reads from global touch 64 cache lines/instruction at 4KB stride ->
// latency-serialized. LDS staging via global_load_lds (coalesced 1KB/op,
// counted vmcnt) is the right design; do NOT remove it.
// Block: 128 q-rows, 8 waves. Deferred-PV pipeline + defer-max (THR=8,
// exp2 domain). V triple-buffered, K double-buffered, counted vmcnt(4).
__global__ __launch_bounds__(512, 4) void attn_kernel(const ushort_t* __restrict__ Q,
                                                      const ushort_t* __restrict__ Kc,
                                                      const ushort_t* __restrict__ Vt,
                                                      ushort_t* __restrict__ Out) {
    __shared__ ushort_t Ks[2 * 64 * 128];   // 32 KiB, swizzled K tiles [key][d]
    __shared__ ushort_t Vs[3 * 128 * 64];   // 48 KiB, swizzled Vt tiles [d][key]
    const int qtb = gridDim.x - 1 - blockIdx.x;  // heavy blocks first
    const int h = blockIdx.y, bb = blockIdx.z;
    const int kvh = h >> 2;
    const int t = threadIdx.x, w = t >> 6, lane = t & 63;
    const int g8 = lane >> 4, l16 = lane & 15;
    const int R = qtb * 128 + w * 16;      // wave q-tile base
    const int qrow = R + l16;              // this lane's softmax row

    const size_t qb = (((size_t)bb * NH + h) * SEQ + R) * HD;
    v8s qf[4];
#pragma unroll
    for (int ks = 0; ks < 4; ++ks)
        qf[ks] = *(const v8s*)&Q[qb + (size_t)l16 * HD + ks * 32 + g8 * 8];

    // hoisted per-lane LDS read offsets (ushort units)
    int kadr[4], vadr[4];
#pragma unroll
    for (int ks = 0; ks < 4; ++ks)
        kadr[ks] = l16 * 128 + (((ks * 4 + g8) ^ l16)) * 8;
    const int vx = (g8 & 1) ^ ((l16 >> 3) & 1);
#pragma unroll
    for (int j = 0; j < 4; ++j)
        vadr[j] = l16 * 64 + (((j * 2 + (g8 >> 1)) ^ (l16 & 7)) * 8) + vx * 4;

    float m_i = -3.0e38f, l_i = 0.f;
    v4f z = {0.f, 0.f, 0.f, 0.f};
    v4f o[8];
#pragma unroll
    for (int n = 0; n < 8; n++) o[n] = z;

    v4s pjp[4];              // P(t-1) carried in registers
    float alo_p[4] = {1.f, 1.f, 1.f, 1.f};
    int skip_p = 1;

    const ushort_t* Kbase = Kc + ((size_t)bb * NKV + kvh) * SEQ * HD;
    const ushort_t* Vbase = Vt + ((size_t)bb * NKV + kvh) * HD * SEQ;

#define STAGE_K(kb, kt)                                                        \
  do {                                                                         \
    const ushort_t* Kt_ = Kbase + (size_t)(kt) * 64 * HD;                      \
    _Pragma("unroll") for (int i_ = 0; i_ < 2; ++i_) {                         \
      int c_ = i_ * 512 + t;                                                   \
      int r_ = c_ >> 4, cc_ = (c_ & 15) ^ (r_ & 15);                           \
      gl2lds16(&Kt_[r_ * 128 + cc_ * 8], &Ks[(kb) * 8192 + c_ * 8]);           \
    }                                                                          \
  } while (0)
#define STAGE_V(vb, kt)                                                        \
  do {                                                                         \
    _Pragma("unroll") for (int i_ = 0; i_ < 2; ++i_) {                         \
      int c_ = i_ * 512 + t;                                                   \
      int d_ = c_ >> 3, cc_ = (c_ & 7) ^ (d_ & 7);                             \
      gl2lds16(&Vbase[(size_t)d_ * SEQ + (kt) * 64 + cc_ * 8],                 \
               &Vs[(vb) * 8192 + c_ * 8]);                                     \
    }                                                                          \
  } while (0)

    const int nkt = 2 * qtb + 2;
    STAGE_K(0, 0); STAGE_V(0, 0);
    asm volatile("s_waitcnt vmcnt(0)" ::: "memory");
    __builtin_amdgcn_s_barrier();

    for (int kt = 0; kt < nkt; ++kt) {
        const int kb = kt & 1;
        const int vbp = (kt + 2) % 3;      // == (kt-1)%3 : V of tile kt-1
        const int k0 = kt * 64;
        if (kt + 1 < nkt) {
            STAGE_K(kb ^ 1, kt + 1);
            STAGE_V((kt + 1) % 3, kt + 1);
            asm volatile("s_waitcnt vmcnt(4)" ::: "memory");  // tile kt landed
        } else {
            asm volatile("s_waitcnt vmcnt(0)" ::: "memory");
        }
        __builtin_amdgcn_s_barrier();

        // ---- QK(t): S^T tiles; lane: q=l16, key=g8*4+r
        v4f s[4];
#pragma unroll
        for (int j = 0; j < 4; j++) s[j] = z;
        __builtin_amdgcn_s_setprio(1);
#pragma unroll
        for (int j = 0; j < 4; j++)
#pragma unroll
            for (int ks = 0; ks < 4; ks++) {
                const v8s kb_ = *(const v8s*)&Ks[kb * 8192 + j * 2048 + kadr[ks]];
                s[j] = __builtin_amdgcn_mfma_f32_16x16x32_bf16(kb_, qf[ks], s[j], 0, 0, 0);
            }
        __builtin_amdgcn_s_setprio(0);

        // ---- deferred rescale + PV(t-1): independent of softmax(t)
        if (kt) {
            if (!skip_p) {
#pragma unroll
                for (int n = 0; n < 8; n++)
#pragma unroll
                    for (int r = 0; r < 4; r++) o[n][r] *= alo_p[r];
            }
            __builtin_amdgcn_s_setprio(1);
#pragma unroll
            for (int j = 0; j < 4; j++)
#pragma unroll
                for (int n = 0; n < 8; n++) {
                    const v4s vb_ = *(const v4s*)&Vs[vbp * 8192 + n * 1024 + vadr[j]];
                    o[n] = MFMA_B16_K16(pjp[j], vb_, o[n]);
                }
            __builtin_amdgcn_s_setprio(0);
        }

        if (kt >= 2 * qtb) {  // diagonal region: causal mask (block-uniform)
#pragma unroll
            for (int j = 0; j < 4; j++)
#pragma unroll
                for (int r = 0; r < 4; r++) {
                    int key = k0 + j * 16 + g8 * 4 + r;
                    if (key > qrow) s[j][r] = -3.0e38f;
                }
        }

        // ---- softmax(t): per-lane max + 2-shfl butterfly across g8 copies
        float mx = fmaxf(fmaxf(s[0][0], s[0][1]), fmaxf(s[0][2], s[0][3]));
#pragma unroll
        for (int j = 1; j < 4; j++)
            mx = fmaxf(mx, fmaxf(fmaxf(s[j][0], s[j][1]), fmaxf(s[j][2], s[j][3])));
        mx = fmaxf(mx, __shfl_xor(mx, 16, 64));
        mx = fmaxf(mx, __shfl_xor(mx, 32, 64));

        const int skip = __all(mx - m_i <= 8.0f);   // defer-max (exp2 domain)
        float alpha = 1.f;
        if (!skip) {
            float mnew = fmaxf(m_i, mx);
            alpha = fast_exp2(m_i - mnew);
            m_i = mnew;
        }

        float sum = 0.f;
#pragma unroll
        for (int j = 0; j < 4; j++)
#pragma unroll
            for (int r = 0; r < 4; r++) {
                float p = fast_exp2(s[j][r] - m_i);
                sum += p;
                pjp[j][r] = (short)f2bf(p);
            }
        sum += __shfl_xor(sum, 16, 64);
        sum += __shfl_xor(sum, 32, 64);
        l_i = l_i * alpha + sum;

        if (!skip) {   // O-row alphas live in lanes 0-15 (rows g8*4+r)
#pragma unroll
            for (int r = 0; r < 4; r++) alo_p[r] = __shfl(alpha, g8 * 4 + r, 64);
        }
        skip_p = skip;

        __builtin_amdgcn_s_barrier();  // all reads of K[kt]/V[kt-1] consumed
    }

    // ---- final deferred PV(nkt-1)
    {
        const int vbl = (nkt + 2) % 3;
        if (!skip_p) {
#pragma unroll
            for (int n = 0; n < 8; n++)
#pragma unroll
                for (int r = 0; r < 4; r++) o[n][r] *= alo_p[r];
        }
#pragma unroll
        for (int j = 0; j < 4; j++)
#pragma unroll
            for (int n = 0; n < 8; n++) {
                const v4s vb_ = *(const v4s*)&Vs[vbl * 8192 + n * 1024 + vadr[j]];
                o[n] = MFMA_B16_K16(pjp[j], vb_, o[n]);
            }
    }
#undef STAGE_K
#undef STAGE_V

    // epilogue: Out[b][s][h][d]; O row g8*4+r = q, col l16 (+16n) = d
    float lo[4];
#pragma unroll
    for (int r = 0; r < 4; r++) lo[r] = __shfl(l_i, g8 * 4 + r, 64);
#pragma unroll
    for (int n = 0; n < 8; n++)
#pragma unroll
        for (int r = 0; r < 4; r++) {
            int row = R + g8 * 4 + r;
            int col = n * 16 + l16;
            Out[(((size_t)bb * SEQ + row) * NH + h) * HD + col] = f2bf(o[n][r] / lo[r]);
        }
}

// ---------------- launch ----------------------------------------------------
extern "C" void kernel_launch(void* const* d_in, const int* in_sizes, int n_in,
                              void* d_out, int out_size, void* d_ws, size_t ws_size,
                              hipStream_t stream) {
    const float* x  = (const float*)d_in[0];
    const float* wq = (const float*)d_in[1];
    const float* wk = (const float*)d_in[2];
    const float* wv = (const float*)d_in[3];
    const float* wo = (const float*)d_in[4];
    const float* fc = (const float*)d_in[5];
    const float* fs = (const float*)d_in[6];
    float* out = (float*)d_out;

    ushort_t* ws = (ushort_t*)d_ws;
    size_t off = 0;
    ushort_t* xb    = ws + off; off += (size_t)NTOK * DIM;   // reused as attn_out
    ushort_t* wqkvb = ws + off; off += (size_t)QKVN * DIM;
    ushort_t* wob   = ws + off; off += (size_t)DIM * DIM;
    ushort_t* qkv   = ws + off; off += (size_t)NTOK * QKVN;
    ushort_t* Qb    = ws + off; off += (size_t)BATCH * NH * SEQ * HD;
    ushort_t* Kb    = ws + off; off += (size_t)BATCH * NKV * SEQ * HD;
    ushort_t* Vt    = ws + off; off += (size_t)BATCH * NKV * HD * SEQ;
    ushort_t* attn_out = xb;  // x dead after QKV GEMM

    cvt_f32_bf16<<<(NTOK * DIM / 4) / 256, 256, 0, stream>>>(x, xb, NTOK * DIM / 4);
    cvt_f32_bf16<<<(DIM * DIM / 4) / 256, 256, 0, stream>>>(wq, wqkvb, DIM * DIM / 4);
    cvt_f32_bf16<<<(NKV * HD * DIM / 4) / 256, 256, 0, stream>>>(
        wk, wqkvb + (size_t)KOFF * DIM, NKV * HD * DIM / 4);
    cvt_f32_bf16<<<(NKV * HD * DIM / 4) / 256, 256, 0, stream>>>(
        wv, wqkvb + (size_t)VOFF * DIM, NKV * HD * DIM / 4);
    cvt_f32_bf16<<<(DIM * DIM / 4) / 256, 256, 0, stream>>>(wo, wob, DIM * DIM / 4);

    dim3 g1(NTOK / 256, QKVN / 256);   // (16, 24) = 384 wgs, %8 == 0
    gemm_bt8<1><<<g1, 512, 0, stream>>>(xb, wqkvb, nullptr, qkv, NTOK, QKVN, DIM);

    rope_reorg<<<NTOK, 256, 0, stream>>>(qkv, fc, fs, Qb, Kb);
    dim3 gv(SEQ / 64, NKV, BATCH);
    v_transpose<<<gv, 256, 0, stream>>>(qkv, Vt);

    dim3 ga(SEQ / 128, NH, BATCH);     // 128 q-rows per block, 8 waves
    attn_kernel<<<ga, 512, 0, stream>>>(Qb, Kb, Vt, attn_out);

    dim3 g2(NTOK / 256, DIM / 256);    // (16, 16) = 256 wgs, %8 == 0
    gemm_bt8<0><<<g2, 512, 0, stream>>>(attn_out, wob, out, nullptr, NTOK, DIM, DIM);
}

// Round 11
// 744.831 us; speedup vs baseline: 2.5135x; 1.0080x over previous
//
#include <hip/hip_runtime.h>
#include <stdint.h>

typedef unsigned short ushort_t;
typedef short v8s __attribute__((ext_vector_type(8)));
typedef short v4s __attribute__((ext_vector_type(4)));
typedef float v4f __attribute__((ext_vector_type(4)));
typedef unsigned int uint32;

#define DIM   4096
#define NH    32
#define NKV   8
#define HD    128
#define SEQ   2048
#define BATCH 2
#define NTOK  (BATCH * SEQ)            // 4096 tokens
#define QKVN  (NH * HD + 2 * NKV * HD) // 6144 = 4096 Q + 1024 K + 1024 V
#define KOFF  (NH * HD)                // 4096
#define VOFF  (NH * HD + NKV * HD)     // 5120

__device__ __forceinline__ ushort_t f2bf(float f) {
    uint32 u = __float_as_uint(f);
    u += 0x7fff + ((u >> 16) & 1);   // RNE
    return (ushort_t)(u >> 16);
}
__device__ __forceinline__ float bf2f(ushort_t h) {
    return __uint_as_float(((uint32)h) << 16);
}
__device__ __forceinline__ void gl2lds16(const void* g, void* l) {
    __builtin_amdgcn_global_load_lds(
        (const __attribute__((address_space(1))) uint32*)g,
        (__attribute__((address_space(3))) uint32*)l, 16, 0, 0);
}
#if __has_builtin(__builtin_amdgcn_exp2f)
__device__ __forceinline__ float fast_exp2(float x) { return __builtin_amdgcn_exp2f(x); }
#else
__device__ __forceinline__ float fast_exp2(float x) { return exp2f(x); }
#endif

// 16x16x16 bf16 MFMA. __has_builtin for amdgcn builtins is 0 in the HOST pass,
// but the host pass still semantic-checks __global__ bodies -> stub must be
// __host__ __device__. Device pass picks the real builtin.
#if !defined(__HIP_DEVICE_COMPILE__)
__host__ __device__ static inline v4f MFMA_B16_K16(v4s a, v4s b, v4f c) {
    (void)a; (void)b; return c;  // host-pass stub, never executed
}
#elif __has_builtin(__builtin_amdgcn_mfma_f32_16x16x16_bf16)
#define MFMA_B16_K16(A, B, C) __builtin_amdgcn_mfma_f32_16x16x16_bf16(A, B, C, 0, 0, 0)
#elif __has_builtin(__builtin_amdgcn_mfma_f32_16x16x16bf16_1k)
#define MFMA_B16_K16(A, B, C) __builtin_amdgcn_mfma_f32_16x16x16bf16_1k(A, B, C, 0, 0, 0)
#else
#error "no 16x16x16 bf16 MFMA builtin on device"
#endif

// ---------------- fp32 -> bf16 convert: ALL 5 input regions in one launch ---
// Region table is compile-time; packs the small wk/wv regions with the big
// ones (fewer launch gaps + better tail packing than 5 separate kernels).
__global__ void cvt_all(const float* __restrict__ x,  const float* __restrict__ wq,
                        const float* __restrict__ wk, const float* __restrict__ wv,
                        const float* __restrict__ wo,
                        ushort_t* __restrict__ xb, ushort_t* __restrict__ wqkvb,
                        ushort_t* __restrict__ wob) {
    const int R0 = NTOK * DIM / 4;                 // x  -> xb
    const int R1 = R0 + DIM * DIM / 4;             // wq -> wqkvb
    const int R2 = R1 + NKV * HD * DIM / 4;        // wk -> wqkvb + KOFF*DIM
    const int R3 = R2 + NKV * HD * DIM / 4;        // wv -> wqkvb + VOFF*DIM
    int i = blockIdx.x * blockDim.x + threadIdx.x;
    const float* src; ushort_t* dst; int off;
    if (i < R0)      { src = x;  dst = xb;                          off = i; }
    else if (i < R1) { src = wq; dst = wqkvb;                       off = i - R0; }
    else if (i < R2) { src = wk; dst = wqkvb + (size_t)KOFF * DIM;  off = i - R1; }
    else if (i < R3) { src = wv; dst = wqkvb + (size_t)VOFF * DIM;  off = i - R2; }
    else             { src = wo; dst = wob;                         off = i - R3; }
    float4 v = ((const float4*)src)[off];
    uint32 lo = ((uint32)f2bf(v.y) << 16) | f2bf(v.x);
    uint32 hi = ((uint32)f2bf(v.w) << 16) | f2bf(v.z);
    ((uint2*)dst)[off] = make_uint2(lo, hi);
}

// ---------------- GEMM: C[M,N] = A[M,K] * B[N,K]^T, 256x256 4-phase/tile ----
// 8 waves (2Mx4N), BK=64, 128 KiB LDS double-buffer. v5 schedule = v3 +
// zero-register A-read reorder (measured ~equal to v3: 41-42% MfmaUtil).
//  NOTE (round 7): do NOT add operand register sets: af 64 + b 32 VGPRs
//  spills past the 128-VGPR cap (acc = 128 AGPRs of the 256-unified file)
//  -> scratch traffic, gemm 211->524 us.
//  vmcnt(6) once per tile proves ALL of tile T+1 before any wave reads it.
template <int OUT_BF16>
__global__ __launch_bounds__(512, 2) void gemm_bt8(const ushort_t* __restrict__ A,
                                                   const ushort_t* __restrict__ B,
                                                   float* __restrict__ Cf,
                                                   ushort_t* __restrict__ Cb,
                                                   int M, int N, int K) {
    __shared__ ushort_t sm[2][2][16384];   // [buf][A|B][256 rows * 64] = 128 KiB
    const int t = threadIdx.x;
    const int w = t >> 6, lane = t & 63;
    const int g8 = lane >> 4, l16 = lane & 15;
    const int wr = w >> 2, wc = w & 3;     // 2 x 4 wave grid

    // XCD-aware swizzle (nwg % 8 == 0 for every launch in this file)
    const int gx = gridDim.x;
    const int nwg = gx * gridDim.y;
    const int wg0 = blockIdx.y * gx + blockIdx.x;
    const int swz = (wg0 & 7) * (nwg >> 3) + (wg0 >> 3);
    const int bm = swz % gx, bn = swz / gx;

    const ushort_t* Ab = A + (size_t)bm * 256 * K;
    const ushort_t* Bb = B + (size_t)bn * 256 * K;

    const int prt = t >> 3;
    const int gg  = (t & 7) ^ (prt & 7);
    const int rA0 = prt,                              rA1 = prt + 128;
    const int rB0 = ((prt >> 5) << 6) + (prt & 31),   rB1 = rB0 + 128;

    const int pgk  = g8 ^ (l16 & 7);          // pg at ks=0; ks=1 -> pgk^4
    const int aoff = (wr * 64 + l16) * 64;
    const int boff = (wc * 32 + l16) * 64;

#define STAGE_A(buf, ah, k0)                                                   \
  do {                                                                         \
    gl2lds16(&Ab[(size_t)(rA0 + (ah) * 64) * K + (k0) + gg * 8],               \
             &sm[buf][0][(ah) * 8192 + t * 8]);                                \
    gl2lds16(&Ab[(size_t)(rA1 + (ah) * 64) * K + (k0) + gg * 8],               \
             &sm[buf][0][(ah) * 8192 + 4096 + t * 8]);                         \
  } while (0)
#define STAGE_B(buf, bh, k0)                                                   \
  do {                                                                         \
    gl2lds16(&Bb[(size_t)(rB0 + (bh) * 32) * K + (k0) + gg * 8],               \
             &sm[buf][1][(bh) * 8192 + t * 8]);                                \
    gl2lds16(&Bb[(size_t)(rB1 + (bh) * 32) * K + (k0) + gg * 8],               \
             &sm[buf][1][(bh) * 8192 + 4096 + t * 8]);                         \
  } while (0)
#define LD_A(dst, buf, ihi)                                                    \
  do {                                                                         \
    _Pragma("unroll") for (int i_ = 0; i_ < 4; ++i_) {                         \
      (dst)[i_ * 2 + 0] = *(const v8s*)&sm[buf][0][(ihi) * 8192 + aoff + i_ * 1024 + pgk * 8];       \
      (dst)[i_ * 2 + 1] = *(const v8s*)&sm[buf][0][(ihi) * 8192 + aoff + i_ * 1024 + (pgk ^ 4) * 8]; \
    }                                                                          \
  } while (0)
#define LD_B(dst, buf, jhi)                                                    \
  do {                                                                         \
    _Pragma("unroll") for (int j_ = 0; j_ < 2; ++j_) {                         \
      (dst)[j_ * 2 + 0] = *(const v8s*)&sm[buf][1][(jhi) * 8192 + boff + j_ * 1024 + pgk * 8];       \
      (dst)[j_ * 2 + 1] = *(const v8s*)&sm[buf][1][(jhi) * 8192 + boff + j_ * 1024 + (pgk ^ 4) * 8]; \
    }                                                                          \
  } while (0)
#define MM(IHI, JHI, AF, BF)                                                   \
  do {                                                                         \
    __builtin_amdgcn_s_setprio(1);                                             \
    _Pragma("unroll") for (int k_ = 0; k_ < 2; ++k_)                           \
      _Pragma("unroll") for (int i_ = 0; i_ < 4; ++i_)                         \
        _Pragma("unroll") for (int j_ = 0; j_ < 2; ++j_)                       \
          acc[(IHI) * 4 + i_][(JHI) * 2 + j_] =                                \
              __builtin_amdgcn_mfma_f32_16x16x32_bf16(                         \
                  (AF)[i_ * 2 + k_], (BF)[j_ * 2 + k_],                        \
                  acc[(IHI) * 4 + i_][(JHI) * 2 + j_], 0, 0, 0);               \
    __builtin_amdgcn_s_setprio(0);                                             \
  } while (0)

// One K-tile. af holds Alo(T) on entry (loaded at prev ph4-end); BL/BH swap
// roles every tile (2-tile unroll).
#define TILE_BODY(T, BF, BL, BH)                                               \
  do {                                                                         \
    const int Tp1 = (T) + 1, Tp2 = (T) + 2;                                    \
    /* ph1: read Bhi; stage B1(T+1); MM00 uses preloaded af(Alo)+BL */         \
    LD_B(BH, BF, 1);                                                           \
    if (Tp1 < nk) STAGE_B((BF) ^ 1, 1, Tp1 << 6);                              \
    MM(0, 0, af, BL);                                                          \
    __builtin_amdgcn_s_barrier();                                              \
    /* ph2: stage A0(T+2); MM01 last use of Alo; then af <- Ahi (WAR) */       \
    if (Tp2 < nk) STAGE_A(BF, 0, Tp2 << 6);                                    \
    MM(0, 1, af, BH);                                                          \
    LD_A(af, BF, 1);                                                           \
    __builtin_amdgcn_s_barrier();                                              \
    /* ph3: stage B0(T+2); MM11 uses af(Ahi, loaded ph2-end) */                \
    if (Tp2 < nk) STAGE_B(BF, 0, Tp2 << 6);                                    \
    MM(1, 1, af, BH);                                                          \
    __builtin_amdgcn_s_barrier();                                              \
    /* ph4: stage A1(T+2); vmcnt proof; MM10 last use of Ahi+BL; then */       \
    /* prefetch next tile's Blo and Alo (buffer proven by the barrier) */      \
    if (Tp2 < nk) STAGE_A(BF, 1, Tp2 << 6);                                    \
    if ((T) < nk - 2) { asm volatile("s_waitcnt vmcnt(6)" ::: "memory"); }     \
    else              { asm volatile("s_waitcnt vmcnt(0)" ::: "memory"); }     \
    __builtin_amdgcn_s_barrier();                                              \
    if (Tp1 < nk) LD_B(BH, (BF) ^ 1, 0); /* next Blo into dead BH */           \
    MM(1, 0, af, BL);                                                          \
    if (Tp1 < nk) LD_A(af, (BF) ^ 1, 0); /* next Alo into af (WAR) */          \
    /* no barrier: MM(1,0) overlaps next tile's ph1 issue */                   \
  } while (0)

    v4f acc[8][4];
    v4f z = {0.f, 0.f, 0.f, 0.f};
#pragma unroll
    for (int i = 0; i < 8; i++)
#pragma unroll
        for (int j = 0; j < 4; j++) acc[i][j] = z;
    v8s af[8], b0[4], b1[4];

    const int nk = K >> 6;

    // prologue: t0 {A0,B0,A1,B1} + t1 {A0,B0,A1}; B1(t1) issues at ph1(t0).
    STAGE_A(0, 0, 0);  STAGE_B(0, 0, 0);  STAGE_A(0, 1, 0);  STAGE_B(0, 1, 0);
    STAGE_A(1, 0, 64); STAGE_B(1, 0, 64); STAGE_A(1, 1, 64);
    asm volatile("s_waitcnt vmcnt(6)" ::: "memory");   // tile0 fully landed
    __builtin_amdgcn_s_barrier();
    LD_A(af, 0, 0);    // Alo(t0)
    LD_B(b0, 0, 0);    // Blo(t0)

    for (int T = 0; T < nk; T += 2) {
        TILE_BODY(T, 0, b0, b1);
        TILE_BODY(T + 1, 1, b1, b0);
    }

#undef STAGE_A
#undef STAGE_B
#undef LD_A
#undef LD_B
#undef MM
#undef TILE_BODY

    const int rowb = bm * 256 + wr * 128;
    const int colb = bn * 256 + wc * 64;
#pragma unroll
    for (int i = 0; i < 8; i++)
#pragma unroll
        for (int j = 0; j < 4; j++)
#pragma unroll
            for (int r = 0; r < 4; r++) {
                int row = rowb + i * 16 + g8 * 4 + r;
                int col = colb + j * 16 + l16;
                float v = acc[i][j][r];
                if (OUT_BF16)
                    Cb[(size_t)row * N + col] = f2bf(v);
                else
                    Cf[(size_t)row * N + col] = v;
            }
}

// ---------------- RoPE + reorg: qkv[tok][6144] -> Q[b,h,s,d], K[b,g,s,d] ----
// Q pre-scaled by (1/sqrt(HD)) * log2(e): softmax runs in exp2 domain.
__global__ __launch_bounds__(256) void rope_reorg(const ushort_t* __restrict__ qkv,
                                                  const float* __restrict__ fc,
                                                  const float* __restrict__ fs,
                                                  ushort_t* __restrict__ Qo,
                                                  ushort_t* __restrict__ Ko) {
    const int tok = blockIdx.x;
    const int bb = tok >> 11, s = tok & 2047;
    const ushort_t* base = qkv + (size_t)tok * QKVN;
    const int t = threadIdx.x;
    const float qscale = 0.08838834764831845f * 1.4426950408889634f;
    uint32* Qw = (uint32*)Qo;
    uint32* Kw = (uint32*)Ko;
#pragma unroll
    for (int i = 0; i < 8; ++i) {
        int p = i * 256 + t;
        int hh = p >> 6, pi = p & 63;
        float c = fc[s * 64 + pi], sn = fs[s * 64 + pi];
        uint32 u = *(const uint32*)&base[hh * 128 + 2 * pi];
        float t0 = bf2f((ushort_t)(u & 0xffff));
        float t1 = bf2f((ushort_t)(u >> 16));
        float o0 = (t0 * c - t1 * sn) * qscale;
        float o1 = (t0 * sn + t1 * c) * qscale;
        size_t dst = (((size_t)bb * NH + hh) * SEQ + s) * HD + 2 * pi;
        Qw[dst >> 1] = ((uint32)f2bf(o1) << 16) | f2bf(o0);
    }
#pragma unroll
    for (int i = 0; i < 2; ++i) {
        int p = i * 256 + t;
        int hh = p >> 6, pi = p & 63;
        float c = fc[s * 64 + pi], sn = fs[s * 64 + pi];
        uint32 u = *(const uint32*)&base[KOFF + hh * 128 + 2 * pi];
        float t0 = bf2f((ushort_t)(u & 0xffff));
        float t1 = bf2f((ushort_t)(u >> 16));
        float o0 = t0 * c - t1 * sn;
        float o1 = t0 * sn + t1 * c;
        size_t dst = (((size_t)bb * NKV + hh) * SEQ + s) * HD + 2 * pi;
        Kw[dst >> 1] = ((uint32)f2bf(o1) << 16) | f2bf(o0);
    }
}

// ---------------- V transpose: qkv V slice -> Vt[b,g,d,s] -------------------
// Rows with (d&8) store each 16B granule with its two 8B halves SWAPPED:
// pairs with the attn V-read sub-granule offset for conflict-free ds_read
// (round 8: SQ_LDS_BANK_CONFLICT 1.78e7 -> 0). Verified value-correct on HW.
__global__ __launch_bounds__(256) void v_transpose(const ushort_t* __restrict__ qkv,
                                                   ushort_t* __restrict__ Vt) {
    __shared__ ushort_t tile[64][136];
    const int st = blockIdx.x, kvh = blockIdx.y, bb = blockIdx.z;
    const int t = threadIdx.x;
    const int s0 = st * 64;
#pragma unroll
    for (int i = 0; i < 4; ++i) {
        int c = i * 256 + t;
        int r = c >> 4, col8 = (c & 15) * 8;
        int tok = (bb << 11) + s0 + r;
        *(v8s*)&tile[r][col8] =
            *(const v8s*)&qkv[(size_t)tok * QKVN + VOFF + kvh * 128 + col8];
    }
    __syncthreads();
#pragma unroll
    for (int i = 0; i < 4; ++i) {
        int c = i * 256 + t;
        int d = c >> 3, s8 = (c & 7) * 8;
        const int hswap = (d & 8) ? 4 : 0;   // swap 8B halves for odd-8 rows
        ushort_t tmp[8];
#pragma unroll
        for (int j = 0; j < 8; j++) tmp[j] = tile[s8 + (j ^ hswap)][d];
        *(v8s*)&Vt[(((size_t)bb * NKV + kvh) * HD + d) * SEQ + s0 + s8] =
            *(v8s*)tmp;
    }
}

// ---------------- Flash attention (causal, GQA) -----------------------------
// SINGLE-BARRIER schedule (round 11): iter t = {vmcnt(0); barrier;
// stage(t+1); QK(t); PV(t-1)+rescale; mask; softmax(t)} -- ONE barrier per
// kv-tile (was 2). Hazard proof: (a) stage K(t+1)->buf (t+1)&1 overwrites
// K[t-1], whose ds_reads every wave consumed before reaching this barrier;
// (b) stage V(t+1)->slot (t+1)%3 overwrites V[t-2] (read in iter t-1,
// barrier-separated); PV(t-1) reads slot (t+2)%3 != (t+1)%3 (triple-buffer);
// (c) vmcnt(0)+barrier proves all waves' stage(t) landed (exactly 4 loads
// outstanding/wave); (d) stage(t+1) has the full iter body as latency cover.
// Round 9 lesson: per-lane direct-global reads are 5.3x slower -- keep
// coalesced global_load_lds staging. Deferred-PV + defer-max (THR=8, exp2
// domain) unchanged -> bitwise-identical results.
__global__ __launch_bounds__(512, 4) void attn_kernel(const ushort_t* __restrict__ Q,
                                                      const ushort_t* __restrict__ Kc,
                                                      const ushort_t* __restrict__ Vt,
                                                      ushort_t* __restrict__ Out) {
    __shared__ ushort_t Ks[2 * 64 * 128];   // 32 KiB, swizzled K tiles [key][d]
    __shared__ ushort_t Vs[3 * 128 * 64];   // 48 KiB, swizzled Vt tiles [d][key]
    const int qtb = gridDim.x - 1 - blockIdx.x;  // heavy blocks first
    const int h = blockIdx.y, bb = blockIdx.z;
    const int kvh = h >> 2;
    const int t = threadIdx.x, w = t >> 6, lane = t & 63;
    const int g8 = lane >> 4, l16 = lane & 15;
    const int R = qtb * 128 + w * 16;      // wave q-tile base
    const int qrow = R + l16;              // this lane's softmax row

    const size_t qb = (((size_t)bb * NH + h) * SEQ + R) * HD;
    v8s qf[4];
#pragma unroll
    for (int ks = 0; ks < 4; ++ks)
        qf[ks] = *(const v8s*)&Q[qb + (size_t)l16 * HD + ks * 32 + g8 * 8];

    // hoisted per-lane LDS read offsets (ushort units)
    int kadr[4], vadr[4];
#pragma unroll
    for (int ks = 0; ks < 4; ++ks)
        kadr[ks] = l16 * 128 + (((ks * 4 + g8) ^ l16)) * 8;
    const int vx = (g8 & 1) ^ ((l16 >> 3) & 1);
#pragma unroll
    for (int j = 0; j < 4; ++j)
        vadr[j] = l16 * 64 + (((j * 2 + (g8 >> 1)) ^ (l16 & 7)) * 8) + vx * 4;

    float m_i = -3.0e38f, l_i = 0.f;
    v4f z = {0.f, 0.f, 0.f, 0.f};
    v4f o[8];
#pragma unroll
    for (int n = 0; n < 8; n++) o[n] = z;

    v4s pjp[4];              // P(t-1) carried in registers
    float alo_p[4] = {1.f, 1.f, 1.f, 1.f};
    int skip_p = 1;

    const ushort_t* Kbase = Kc + ((size_t)bb * NKV + kvh) * SEQ * HD;
    const ushort_t* Vbase = Vt + ((size_t)bb * NKV + kvh) * HD * SEQ;

#define STAGE_K(kb, kt)                                                        \
  do {                                                                         \
    const ushort_t* Kt_ = Kbase + (size_t)(kt) * 64 * HD;                      \
    _Pragma("unroll") for (int i_ = 0; i_ < 2; ++i_) {                         \
      int c_ = i_ * 512 + t;                                                   \
      int r_ = c_ >> 4, cc_ = (c_ & 15) ^ (r_ & 15);                           \
      gl2lds16(&Kt_[r_ * 128 + cc_ * 8], &Ks[(kb) * 8192 + c_ * 8]);           \
    }                                                                          \
  } while (0)
#define STAGE_V(vb, kt)                                                        \
  do {                                                                         \
    _Pragma("unroll") for (int i_ = 0; i_ < 2; ++i_) {                         \
      int c_ = i_ * 512 + t;                                                   \
      int d_ = c_ >> 3, cc_ = (c_ & 7) ^ (d_ & 7);                             \
      gl2lds16(&Vbase[(size_t)d_ * SEQ + (kt) * 64 + cc_ * 8],                 \
               &Vs[(vb) * 8192 + c_ * 8]);                                     \
    }                                                                          \
  } while (0)

    const int nkt = 2 * qtb + 2;
    STAGE_K(0, 0); STAGE_V(0, 0);

    for (int kt = 0; kt < nkt; ++kt) {
        const int kb = kt & 1;
        const int vbp = (kt + 2) % 3;      // == (kt-1)%3 : V of tile kt-1
        const int k0 = kt * 64;

        // single sync point: prove stage(kt) landed for ALL waves
        asm volatile("s_waitcnt vmcnt(0)" ::: "memory");
        __builtin_amdgcn_s_barrier();
        if (kt + 1 < nkt) {                // full-iter latency cover
            STAGE_K(kb ^ 1, kt + 1);
            STAGE_V((kt + 1) % 3, kt + 1);
        }

        // ---- QK(t): S^T tiles; lane: q=l16, key=g8*4+r
        v4f s[4];
#pragma unroll
        for (int j = 0; j < 4; j++) s[j] = z;
        __builtin_amdgcn_s_setprio(1);
#pragma unroll
        for (int j = 0; j < 4; j++)
#pragma unroll
            for (int ks = 0; ks < 4; ks++) {
                const v8s kb_ = *(const v8s*)&Ks[kb * 8192 + j * 2048 + kadr[ks]];
                s[j] = __builtin_amdgcn_mfma_f32_16x16x32_bf16(kb_, qf[ks], s[j], 0, 0, 0);
            }
        __builtin_amdgcn_s_setprio(0);

        // ---- deferred rescale + PV(t-1): independent of softmax(t)
        if (kt) {
            if (!skip_p) {
#pragma unroll
                for (int n = 0; n < 8; n++)
#pragma unroll
                    for (int r = 0; r < 4; r++) o[n][r] *= alo_p[r];
            }
            __builtin_amdgcn_s_setprio(1);
#pragma unroll
            for (int j = 0; j < 4; j++)
#pragma unroll
                for (int n = 0; n < 8; n++) {
                    const v4s vb_ = *(const v4s*)&Vs[vbp * 8192 + n * 1024 + vadr[j]];
                    o[n] = MFMA_B16_K16(pjp[j], vb_, o[n]);
                }
            __builtin_amdgcn_s_setprio(0);
        }

        if (kt >= 2 * qtb) {  // diagonal region: causal mask (block-uniform)
#pragma unroll
            for (int j = 0; j < 4; j++)
#pragma unroll
                for (int r = 0; r < 4; r++) {
                    int key = k0 + j * 16 + g8 * 4 + r;
                    if (key > qrow) s[j][r] = -3.0e38f;
                }
        }

        // ---- softmax(t): per-lane max + 2-shfl butterfly across g8 copies
        float mx = fmaxf(fmaxf(s[0][0], s[0][1]), fmaxf(s[0][2], s[0][3]));
#pragma unroll
        for (int j = 1; j < 4; j++)
            mx = fmaxf(mx, fmaxf(fmaxf(s[j][0], s[j][1]), fmaxf(s[j][2], s[j][3])));
        mx = fmaxf(mx, __shfl_xor(mx, 16, 64));
        mx = fmaxf(mx, __shfl_xor(mx, 32, 64));

        const int skip = __all(mx - m_i <= 8.0f);   // defer-max (exp2 domain)
        float alpha = 1.f;
        if (!skip) {
            float mnew = fmaxf(m_i, mx);
            alpha = fast_exp2(m_i - mnew);
            m_i = mnew;
        }

        float sum = 0.f;
#pragma unroll
        for (int j = 0; j < 4; j++)
#pragma unroll
            for (int r = 0; r < 4; r++) {
                float p = fast_exp2(s[j][r] - m_i);
                sum += p;
                pjp[j][r] = (short)f2bf(p);
            }
        sum += __shfl_xor(sum, 16, 64);
        sum += __shfl_xor(sum, 32, 64);
        l_i = l_i * alpha + sum;

        if (!skip) {   // O-row alphas live in lanes 0-15 (rows g8*4+r)
#pragma unroll
            for (int r = 0; r < 4; r++) alo_p[r] = __shfl(alpha, g8 * 4 + r, 64);
        }
        skip_p = skip;
        // no end-of-iter barrier: next iter's vmcnt(0)+barrier is the sync
    }

    // ---- final deferred PV(nkt-1)
    {
        const int vbl = (nkt + 2) % 3;
        if (!skip_p) {
#pragma unroll
            for (int n = 0; n < 8; n++)
#pragma unroll
                for (int r = 0; r < 4; r++) o[n][r] *= alo_p[r];
        }
#pragma unroll
        for (int j = 0; j < 4; j++)
#pragma unroll
            for (int n = 0; n < 8; n++) {
                const v4s vb_ = *(const v4s*)&Vs[vbl * 8192 + n * 1024 + vadr[j]];
                o[n] = MFMA_B16_K16(pjp[j], vb_, o[n]);
            }
    }
#undef STAGE_K
#undef STAGE_V

    // epilogue: Out[b][s][h][d]; O row g8*4+r = q, col l16 (+16n) = d
    float lo[4];
#pragma unroll
    for (int r = 0; r < 4; r++) lo[r] = __shfl(l_i, g8 * 4 + r, 64);
#pragma unroll
    for (int n = 0; n < 8; n++)
#pragma unroll
        for (int r = 0; r < 4; r++) {
            int row = R + g8 * 4 + r;
            int col = n * 16 + l16;
            Out[(((size_t)bb * SEQ + row) * NH + h) * HD + col] = f2bf(o[n][r] / lo[r]);
        }
}

// ---------------- launch ----------------------------------------------------
extern "C" void kernel_launch(void* const* d_in, const int* in_sizes, int n_in,
                              void* d_out, int out_size, void* d_ws, size_t ws_size,
                              hipStream_t stream) {
    const float* x  = (const float*)d_in[0];
    const float* wq = (const float*)d_in[1];
    const float* wk = (const float*)d_in[2];
    const float* wv = (const float*)d_in[3];
    const float* wo = (const float*)d_in[4];
    const float* fc = (const float*)d_in[5];
    const float* fs = (const float*)d_in[6];
    float* out = (float*)d_out;

    ushort_t* ws = (ushort_t*)d_ws;
    size_t off = 0;
    ushort_t* xb    = ws + off; off += (size_t)NTOK * DIM;   // reused as attn_out
    ushort_t* wqkvb = ws + off; off += (size_t)QKVN * DIM;
    ushort_t* wob   = ws + off; off += (size_t)DIM * DIM;
    ushort_t* qkv   = ws + off; off += (size_t)NTOK * QKVN;
    ushort_t* Qb    = ws + off; off += (size_t)BATCH * NH * SEQ * HD;
    ushort_t* Kb    = ws + off; off += (size_t)BATCH * NKV * SEQ * HD;
    ushort_t* Vt    = ws + off; off += (size_t)BATCH * NKV * HD * SEQ;
    ushort_t* attn_out = xb;  // x dead after QKV GEMM

    // one launch converts all 5 fp32 regions (x, wq, wk, wv, wo)
    const int cvt_n4 = (NTOK * DIM + 2 * DIM * DIM + 2 * NKV * HD * DIM) / 4;
    cvt_all<<<cvt_n4 / 256, 256, 0, stream>>>(x, wq, wk, wv, wo, xb, wqkvb, wob);

    dim3 g1(NTOK / 256, QKVN / 256);   // (16, 24) = 384 wgs, %8 == 0
    gemm_bt8<1><<<g1, 512, 0, stream>>>(xb, wqkvb, nullptr, qkv, NTOK, QKVN, DIM);

    rope_reorg<<<NTOK, 256, 0, stream>>>(qkv, fc, fs, Qb, Kb);
    dim3 gv(SEQ / 64, NKV, BATCH);
    v_transpose<<<gv, 256, 0, stream>>>(qkv, Vt);

    dim3 ga(SEQ / 128, NH, BATCH);     // 128 q-rows per block, 8 waves
    attn_kernel<<<ga, 512, 0, stream>>>(Qb, Kb, Vt, attn_out);

    dim3 g2(NTOK / 256, DIM / 256);    // (16, 16) = 256 wgs, %8 == 0
    gemm_bt8<0><<<g2, 512, 0, stream>>>(attn_out, wob, out, nullptr, NTOK, DIM, DIM);
}